// Round 17
// baseline (356.510 us; speedup 1.0000x reference)
//
#include <hip/hip_runtime.h>
#include <math.h>

constexpr int NN  = 50000;   // nodes
constexpr int EE  = 800000;  // edges
constexpr int NPAD = 50176;  // NN padded to 1024 multiple
constexpr float LOG2E = 1.4426950408889634f;
constexpr int CST = 16;      // counts stride (ints): 1 counter per 64B line
constexpr int EBLK = 625;    // edge-pass blocks: 625*256*5 == EE exactly

typedef short bf16x8 __attribute__((ext_vector_type(8)));
typedef float f32x4  __attribute__((ext_vector_type(4)));

__device__ __forceinline__ unsigned f2bfu(float f) {
    union { float f; unsigned u; } x; x.f = f;
    unsigned r = x.u + 0x7fffu + ((x.u >> 16) & 1u);
    return r >> 16;
}
__device__ __forceinline__ short f2bf(float f) { return (short)f2bfu(f); }
__device__ __forceinline__ unsigned pack2(float lo, float hi) {
    return f2bfu(lo) | (f2bfu(hi) << 16);
}
__device__ __forceinline__ float bfbits_lo(unsigned w) { return __uint_as_float(w << 16); }
__device__ __forceinline__ float bfbits_hi(unsigned w) { return __uint_as_float(w & 0xffff0000u); }

__device__ __forceinline__ float gelu_tanh(float x) {
    float u = 0.7978845608028654f * (x + 0.044715f * x * x * x);
    float t = 1.0f - 2.0f / (__expf(2.0f * u) + 1.0f);   // tanh(u)
    return 0.5f * x * (1.0f + t);
}

// 16-lane (DPP-row) sum reduce, broadcast to all 16 lanes.
__device__ __forceinline__ float dpp_add16(float x) {
    int t;
    t = __builtin_amdgcn_update_dpp(0, __float_as_int(x), 0xB1,  0xf, 0xf, true);
    x += __int_as_float(t);
    t = __builtin_amdgcn_update_dpp(0, __float_as_int(x), 0x4E,  0xf, 0xf, true);
    x += __int_as_float(t);
    t = __builtin_amdgcn_update_dpp(0, __float_as_int(x), 0x141, 0xf, 0xf, true);
    x += __int_as_float(t);
    t = __builtin_amdgcn_update_dpp(0, __float_as_int(x), 0x140, 0xf, 0xf, true);
    x += __int_as_float(t);
    return x;
}

// 8-lane sum reduce (xor1, xor2, half-row mirror), broadcast to the 8 lanes.
__device__ __forceinline__ float dpp_add8(float x) {
    int t;
    t = __builtin_amdgcn_update_dpp(0, __float_as_int(x), 0xB1,  0xf, 0xf, true);
    x += __int_as_float(t);
    t = __builtin_amdgcn_update_dpp(0, __float_as_int(x), 0x4E,  0xf, 0xf, true);
    x += __int_as_float(t);
    t = __builtin_amdgcn_update_dpp(0, __float_as_int(x), 0x141, 0xf, 0xf, true);
    x += __int_as_float(t);
    return x;
}

// -------- weight prep args --------
struct WtArgs {
    const float* src[10];
    short*       dst[10];
    int K[10];
    int N[10];
};

// -------- [LN] + 1-2 bf16 MFMA GEMMs (BN=128, K=128), LOW-LDS variant --------
// B staged in four 32-row quarters (Bs = 32x136 bf16) -> 26 KB LDS, 6 blocks/CU.
template<int NB, int DO_LN, int ACT, int OUTBF0, int OUTBF1>
__device__ __forceinline__ void ln_gemm_body(
    int row0, const float* __restrict__ A,
    const float* __restrict__ lg, const float* __restrict__ lb,
    const short* __restrict__ B0t, const float* __restrict__ bias0, void* __restrict__ C0,
    const short* __restrict__ B1t, const float* __restrict__ bias1, void* __restrict__ C1,
    int nrows, short* As /*[64*136]*/, short* Bs /*[32*136]*/)
{
    constexpr int K = 128, KP = 136, BN = 128;
    constexpr int CH = K / 8;           // 16 chunks/row
    const int tid = threadIdx.x;

    // ---- phase 1: load A (4 threads/row), optional LN, pack bf16 -> As ----
    {
        int r = tid >> 2, q = tid & 3;
        int grow = row0 + r;
        bool ok = grow < nrows;
        float4 v[8];
        const float* src = A + (size_t)grow * K + q * 32;
#pragma unroll
        for (int i = 0; i < 8; ++i)
            v[i] = ok ? *reinterpret_cast<const float4*>(src + i * 4)
                      : make_float4(0.f, 0.f, 0.f, 0.f);
        if (DO_LN) {
            float s = 0.f, s2 = 0.f;
#pragma unroll
            for (int i = 0; i < 8; ++i) {
                s  += v[i].x + v[i].y + v[i].z + v[i].w;
                s2 += v[i].x * v[i].x + v[i].y * v[i].y + v[i].z * v[i].z + v[i].w * v[i].w;
            }
            s += __shfl_xor(s, 1); s2 += __shfl_xor(s2, 1);
            s += __shfl_xor(s, 2); s2 += __shfl_xor(s2, 2);
            float mean = s * (1.f / 128.f);
            float var  = s2 * (1.f / 128.f) - mean * mean;
            float rstd = rsqrtf(var + 1e-5f);
#pragma unroll
            for (int i = 0; i < 8; ++i) {
                float4 gg = *reinterpret_cast<const float4*>(lg + q * 32 + i * 4);
                float4 bb = *reinterpret_cast<const float4*>(lb + q * 32 + i * 4);
                v[i].x = (v[i].x - mean) * rstd * gg.x + bb.x;
                v[i].y = (v[i].y - mean) * rstd * gg.y + bb.y;
                v[i].z = (v[i].z - mean) * rstd * gg.z + bb.z;
                v[i].w = (v[i].w - mean) * rstd * gg.w + bb.w;
            }
        }
        short* dst = &As[r * KP + q * 32];
#pragma unroll
        for (int i = 0; i < 4; ++i) {
            uint4 w = make_uint4(pack2(v[2*i].x,   v[2*i].y),
                                 pack2(v[2*i].z,   v[2*i].w),
                                 pack2(v[2*i+1].x, v[2*i+1].y),
                                 pack2(v[2*i+1].z, v[2*i+1].w));
            *reinterpret_cast<uint4*>(dst + i * 8) = w;
        }
    }
    __syncthreads();                    // As visible to all waves

    const int wave = tid >> 6;
    const int lane = tid & 63;
    const int kg   = lane >> 4;
    const int lr   = lane & 15;

    bf16x8 afrag[4];
#pragma unroll
    for (int kk = 0; kk < 4; ++kk)
        afrag[kk] = *reinterpret_cast<const bf16x8*>(
            &As[(wave * 16 + lr) * KP + kk * 32 + kg * 8]);

    // stage 32 rows (quarter q) of a [128][128] bf16 weight into Bs
    auto stageBq = [&](const short* __restrict__ Bt, int q) {
#pragma unroll
        for (int it = 0; it < 2; ++it) {
            int idx = tid + it * 256;          // 0..511
            int nn = idx / CH, j = idx % CH;   // nn 0..31
            *reinterpret_cast<uint4*>(&Bs[nn * KP + j * 8]) =
                *reinterpret_cast<const uint4*>(&Bt[(q * 32 + nn) * K + j * 8]);
        }
    };

    auto do_gemm = [&](const short* __restrict__ Bt,
                       const float* __restrict__ bias, void* __restrict__ Cv, bool outbf) {
        f32x4 acc[8];
#pragma unroll
        for (int nf = 0; nf < 8; ++nf) acc[nf] = (f32x4){0.f, 0.f, 0.f, 0.f};
#pragma unroll
        for (int q = 0; q < 4; ++q) {
            __syncthreads();            // previous quarter's reads done
            stageBq(Bt, q);
            __syncthreads();
#pragma unroll
            for (int l = 0; l < 2; ++l) {
                int nf = q * 2 + l;
#pragma unroll
                for (int kk = 0; kk < 4; ++kk) {
                    bf16x8 bfrag = *reinterpret_cast<const bf16x8*>(
                        &Bs[(l * 16 + lr) * KP + kk * 32 + kg * 8]);
                    acc[nf] = __builtin_amdgcn_mfma_f32_16x16x32_bf16(
                        afrag[kk], bfrag, acc[nf], 0, 0, 0);
                }
            }
        }
#pragma unroll
        for (int nf = 0; nf < 8; ++nf) {
            int col = nf * 16 + lr;
            float bi = bias[col];
#pragma unroll
            for (int j = 0; j < 4; ++j) {
                int row = row0 + wave * 16 + kg * 4 + j;
                if (row < nrows) {
                    float v = acc[nf][j] + bi;
                    if (ACT == 1) v = gelu_tanh(v);
                    if (outbf) ((short*)Cv)[(size_t)row * BN + col] = f2bf(v);
                    else       ((float*)Cv)[(size_t)row * BN + col] = v;
                }
            }
        }
    };

    do_gemm(B0t, bias0, C0, OUTBF0 != 0);
    if (NB == 2)
        do_gemm(B1t, bias1, C1, OUTBF1 != 0);
}

// ---------------- hybrid1: pos atomics (EBLK blocks, unrolled x5) || weight prep ----------------
__global__ __launch_bounds__(256) void hybrid1(
    const int* __restrict__ ei, int* __restrict__ counts, int* __restrict__ pos, WtArgs a)
{
    if (blockIdx.x < EBLK) {
        int e0 = blockIdx.x * 256 + threadIdx.x;
#pragma unroll
        for (int i = 0; i < 5; ++i) {
            int e = e0 + i * EBLK * 256;
            pos[e] = atomicAdd(&counts[(size_t)ei[EE + e] * CST], 1);
        }
    } else {
        int bb = blockIdx.x - EBLK;
        int m = bb >> 4, slice = bb & 15;
        const float* s = a.src[m];
        short* d = a.dst[m];
        int K = a.K[m], N = a.N[m], total = K * N;
        for (int i = slice * 256 + threadIdx.x; i < total; i += 16 * 256) {
            int k = i / N, n = i - k * N;
            d[n * K + k] = f2bf(s[i]);
        }
    }
}

// ---------------- compact: cc[i] = counts[i*CST], massively parallel ----------------
__global__ __launch_bounds__(256) void compact_kernel(
    const int* __restrict__ counts, int* __restrict__ cc)
{
    int i = blockIdx.x * 256 + threadIdx.x;
    if (i < NPAD) cc[i] = counts[(size_t)i * CST];
}

// ---------------- scan (1 block, 256 threads, 4 elems/thread, contiguous cc) ----------------
__device__ void scan256(const int* __restrict__ cc, int* __restrict__ roff) {
    __shared__ int wsum[4];
    __shared__ int tilesum;
    int tid = threadIdx.x, wid = tid >> 6, lane = tid & 63;
    int carry = 0;
    for (int base = 0; base < NPAD; base += 1024) {
        int idx = base + tid * 4;
        int4 c = *reinterpret_cast<const int4*>(&cc[idx]);
        int s0 = c.x, s1 = s0 + c.y, s2 = s1 + c.z, s3 = s2 + c.w;
        int x = s3;
#pragma unroll
        for (int off = 1; off < 64; off <<= 1) {
            int t = __shfl_up(x, off);
            if (lane >= off) x += t;
        }
        if (lane == 63) wsum[wid] = x;
        __syncthreads();
        if (tid == 0) {
            int a0 = wsum[0], a1 = wsum[1], a2 = wsum[2], a3 = wsum[3];
            wsum[0] = 0; wsum[1] = a0; wsum[2] = a0 + a1; wsum[3] = a0 + a1 + a2;
            tilesum = a0 + a1 + a2 + a3;
        }
        __syncthreads();
        int start = carry + wsum[wid] + (x - s3);      // exclusive prefix at idx
        int4 o = make_int4(start, start + s0, start + s1, start + s2);
        *reinterpret_cast<int4*>(&roff[idx]) = o;
        carry += tilesum;
        __syncthreads();
    }
}

// ---------------- hybrid2: scan (block 0) || input projection ----------------
__global__ __launch_bounds__(256) void hybrid2(
    const int* __restrict__ cc, int* __restrict__ roff,
    const float* __restrict__ x, const short* __restrict__ Win_t,
    const float* __restrict__ b_in, float* __restrict__ h, int nrows)
{
    __shared__ short As[64 * 136];
    __shared__ short Bs[32 * 136];
    if (blockIdx.x == 0) {
        scan256(cc, roff);
    } else {
        ln_gemm_body<1, 0, 0, 0, 0>((blockIdx.x - 1) * 64, x, nullptr,
            nullptr, Win_t, b_in, h, nullptr, nullptr, nullptr, nrows, As, Bs);
    }
}

// ---------------- hybrid3: scatter (EBLK blocks, unrolled x5) || layer-0 LN+GEMMs ----------------
__global__ __launch_bounds__(256) void hybrid3(
    const int* __restrict__ ei, const int* __restrict__ roff,
    const int* __restrict__ pos, int* __restrict__ ssrc,
    const float* __restrict__ h, const float* __restrict__ lg, const float* __restrict__ lb,
    const short* __restrict__ Wl_t, const float* __restrict__ bl, short* __restrict__ XL,
    const short* __restrict__ Wr_t, const float* __restrict__ br, short* __restrict__ XR,
    int nrows)
{
    __shared__ short As[64 * 136];
    __shared__ short Bs[32 * 136];
    if (blockIdx.x < EBLK) {
        int e0 = blockIdx.x * 256 + threadIdx.x;
        // 5 fully-independent load->store chains per lane (latency hiding)
        int d[5], p[5], s[5];
#pragma unroll
        for (int i = 0; i < 5; ++i) {
            int e = e0 + i * EBLK * 256;
            d[i] = ei[EE + e];
            p[i] = pos[e];
            s[i] = ei[e] << 8;           // pre-shifted byte offset
        }
#pragma unroll
        for (int i = 0; i < 5; ++i)
            ssrc[roff[d[i]] + p[i]] = s[i];
    } else {
        ln_gemm_body<2, 1, 0, 1, 1>((blockIdx.x - EBLK) * 64, h,
            lg, lb, Wl_t, bl, XL, Wr_t, br, XR, nrows, As, Bs);
    }
}

// ---------------- standalone fused LN + Wl/Wr GEMMs (layers 1,2) ----------------
__global__ __launch_bounds__(256) void fused_layer(
    const float* __restrict__ h, const float* __restrict__ lg, const float* __restrict__ lb,
    const short* __restrict__ Wl_t, const float* __restrict__ bl, short* __restrict__ XL,
    const short* __restrict__ Wr_t, const float* __restrict__ br, short* __restrict__ XR,
    int nrows)
{
    __shared__ short As[64 * 136];
    __shared__ short Bs[32 * 136];
    ln_gemm_body<2, 1, 0, 1, 1>(blockIdx.x * 64, h, lg, lb,
        Wl_t, bl, XL, Wr_t, br, XR, nrows, As, Bs);
}

// ---------------- Fused GATv2 aggregation, one wave per node (R13/R14 version) ----------------
__global__ __launch_bounds__(256) void gat_node_kernel(
    const short* __restrict__ XL, const short* __restrict__ XR,
    const int* __restrict__ roff, const int* __restrict__ ssrc,
    const float* __restrict__ att, const float* __restrict__ conv_b,
    float* __restrict__ h)
{
    int n = blockIdx.x * 4 + (threadIdx.x >> 6);
    if (n >= NN) return;
    const int lane = threadIdx.x & 63;
    const int half = lane >> 5;          // edge slot within a pass
    const int pos  = lane & 31;          // channels pos*4 .. pos*4+3

    uint2 wr2 = *reinterpret_cast<const uint2*>(&XR[(size_t)n * 128 + pos * 4]);
    const float xr0 = bfbits_lo(wr2.x), xr1 = bfbits_hi(wr2.x);
    const float xr2 = bfbits_lo(wr2.y), xr3 = bfbits_hi(wr2.y);
    float4 at = *reinterpret_cast<const float4*>(&att[pos * 4]);
    const float a6_0 = at.x * (0.6f * LOG2E), a4_0 = at.x * (0.4f * LOG2E);
    const float a6_1 = at.y * (0.6f * LOG2E), a4_1 = at.y * (0.4f * LOG2E);
    const float a6_2 = at.z * (0.6f * LOG2E), a4_2 = at.z * (0.4f * LOG2E);
    const float a6_3 = at.w * (0.6f * LOG2E), a4_3 = at.w * (0.4f * LOG2E);

    float dA = 0.f, dB = 0.f;
    float aA0 = 0.f, aA1 = 0.f, aA2 = 0.f, aA3 = 0.f;
    float aB0 = 0.f, aB1 = 0.f, aB2 = 0.f, aB3 = 0.f;

    const char* XLb = (const char*)XL;
    const unsigned lbyte = (unsigned)pos * 8u;

    auto proc = [&](uint2 w, bool valid, float& d,
                    float& a0, float& a1, float& a2, float& a3) {
        float x0 = bfbits_lo(w.x), x1 = bfbits_hi(w.x);
        float x2 = bfbits_lo(w.y), x3 = bfbits_hi(w.y);
        float s0 = x0 + xr0, s1 = x1 + xr1, s2 = x2 + xr2, s3 = x3 + xr3;
        float part =
            fmaf(s0, a6_0, fmaf(__builtin_fabsf(s0), a4_0,
            fmaf(s1, a6_1, fmaf(__builtin_fabsf(s1), a4_1,
            fmaf(s2, a6_2, fmaf(__builtin_fabsf(s2), a4_2,
            fmaf(s3, a6_3, __builtin_fabsf(s3) * a4_3)))))));
        part = dpp_add8(part);               // head dot: 8 lanes x 4 ch
        float pe = __builtin_amdgcn_exp2f(part);
        if (!valid) pe = 0.f;
        d += pe;
        a0 = fmaf(pe, x0, a0);
        a1 = fmaf(pe, x1, a1);
        a2 = fmaf(pe, x2, a2);
        a3 = fmaf(pe, x3, a3);
    };

    const int beg = roff[n], end = roff[n + 1];
    int p = beg;
    for (; p + 3 < end; p += 4) {
        unsigned oA = (unsigned)ssrc[p + half]     + lbyte;
        unsigned oB = (unsigned)ssrc[p + 2 + half] + lbyte;
        uint2 wA = *reinterpret_cast<const uint2*>(XLb + oA);
        uint2 wB = *reinterpret_cast<const uint2*>(XLb + oB);
        proc(wA, true, dA, aA0, aA1, aA2, aA3);
        proc(wB, true, dB, aB0, aB1, aB2, aB3);
    }
    if (p < end) {
        int eA = p + half;
        bool vA = eA < end;
        unsigned oA = (unsigned)ssrc[vA ? eA : beg] + lbyte;
        uint2 wA = *reinterpret_cast<const uint2*>(XLb + oA);
        proc(wA, vA, dA, aA0, aA1, aA2, aA3);
        if (p + 2 < end) {
            int eB = p + 2 + half;
            bool vB = eB < end;
            unsigned oB = (unsigned)ssrc[vB ? eB : beg] + lbyte;
            uint2 wB = *reinterpret_cast<const uint2*>(XLb + oB);
            proc(wB, vB, dB, aB0, aB1, aB2, aB3);
        }
    }
    float d  = dA + dB;
    float c0 = aA0 + aB0, c1 = aA1 + aB1, c2 = aA2 + aB2, c3 = aA3 + aB3;
    d  += __shfl_xor(d, 32);
    c0 += __shfl_xor(c0, 32);
    c1 += __shfl_xor(c1, 32);
    c2 += __shfl_xor(c2, 32);
    c3 += __shfl_xor(c3, 32);

    if (half == 0) {
        float inv = 1.f / (d + 1e-16f);
        float* hp = &h[(size_t)n * 128 + pos * 4];
        float4 hv = *reinterpret_cast<const float4*>(hp);
        float4 cb = *reinterpret_cast<const float4*>(&conv_b[pos * 4]);
        hv.x += gelu_tanh(fmaf(c0, inv, cb.x));
        hv.y += gelu_tanh(fmaf(c1, inv, cb.y));
        hv.z += gelu_tanh(fmaf(c2, inv, cb.z));
        hv.w += gelu_tanh(fmaf(c3, inv, cb.w));
        *reinterpret_cast<float4*>(hp) = hv;
    }
}

// -------- final: LN -> {prob head fused, vol = gelu(z@vW1+vb1) @ vW2 + vb2} --------
__global__ __launch_bounds__(256) void final_head_full(
    const float* __restrict__ A,
    const float* __restrict__ lg, const float* __restrict__ lb,
    const short* __restrict__ pW1t, const float* __restrict__ pb1,
    const float* __restrict__ pW2, const float* __restrict__ pb2,
    const short* __restrict__ vW1t, const float* __restrict__ vb1,
    const short* __restrict__ vW2t, const float* __restrict__ vb2,
    float* __restrict__ vol, float* __restrict__ prob, int nrows)
{
    constexpr int K = 128, KP = 136, KP2 = 72;
    constexpr int CH = K / 8;
    __shared__ short As[64 * 136];   // LN'd input; later reused as t2 tile [64][72]
    __shared__ short Bs[128 * 136];  // pW1t rows 0-63, vW1t rows 64-127; later vW2t

    const int tid  = threadIdx.x;
    const int row0 = blockIdx.x * 64;

    // LN -> As
    {
        int r = tid >> 2, q = tid & 3;
        int grow = row0 + r;
        bool ok = grow < nrows;
        float4 v[8];
        const float* src = A + (size_t)grow * K + q * 32;
#pragma unroll
        for (int i = 0; i < 8; ++i)
            v[i] = ok ? *reinterpret_cast<const float4*>(src + i * 4)
                      : make_float4(0.f, 0.f, 0.f, 0.f);
        float s = 0.f, s2 = 0.f;
#pragma unroll
        for (int i = 0; i < 8; ++i) {
            s  += v[i].x + v[i].y + v[i].z + v[i].w;
            s2 += v[i].x * v[i].x + v[i].y * v[i].y + v[i].z * v[i].z + v[i].w * v[i].w;
        }
        s += __shfl_xor(s, 1); s2 += __shfl_xor(s2, 1);
        s += __shfl_xor(s, 2); s2 += __shfl_xor(s2, 2);
        float mean = s * (1.f / 128.f);
        float var  = s2 * (1.f / 128.f) - mean * mean;
        float rstd = rsqrtf(var + 1e-5f);
        short* dst = &As[r * KP + q * 32];
#pragma unroll
        for (int i = 0; i < 8; ++i) {
            float4 gg = *reinterpret_cast<const float4*>(lg + q * 32 + i * 4);
            float4 bb = *reinterpret_cast<const float4*>(lb + q * 32 + i * 4);
            v[i].x = (v[i].x - mean) * rstd * gg.x + bb.x;
            v[i].y = (v[i].y - mean) * rstd * gg.y + bb.y;
            v[i].z = (v[i].z - mean) * rstd * gg.z + bb.z;
            v[i].w = (v[i].w - mean) * rstd * gg.w + bb.w;
        }
#pragma unroll
        for (int i = 0; i < 4; ++i) {
            uint4 w = make_uint4(pack2(v[2*i].x,   v[2*i].y),
                                 pack2(v[2*i].z,   v[2*i].w),
                                 pack2(v[2*i+1].x, v[2*i+1].y),
                                 pack2(v[2*i+1].z, v[2*i+1].w));
            *reinterpret_cast<uint4*>(dst + i * 8) = w;
        }
    }
    // stage pW1t | vW1t
#pragma unroll
    for (int it = 0; it < 8; ++it) {
        int idx = tid + it * 256;
        int nn = idx / CH, j = idx % CH;
        const short* srcw = (nn < 64) ? &pW1t[nn * K + j * 8]
                                      : &vW1t[(nn - 64) * K + j * 8];
        *reinterpret_cast<uint4*>(&Bs[nn * KP + j * 8]) =
            *reinterpret_cast<const uint4*>(srcw);
    }
    __syncthreads();

    const int wave = tid >> 6;
    const int lane = tid & 63;
    const int kg   = lane >> 4;
    const int lr   = lane & 15;

    bf16x8 afrag[4];
#pragma unroll
    for (int kk = 0; kk < 4; ++kk)
        afrag[kk] = *reinterpret_cast<const bf16x8*>(
            &As[(wave * 16 + lr) * KP + kk * 32 + kg * 8]);

    // ---- vW1 GEMM -> acc_v (keep in regs) ----
    f32x4 acc_v[4];
#pragma unroll
    for (int nf = 0; nf < 4; ++nf) acc_v[nf] = (f32x4){0.f, 0.f, 0.f, 0.f};
#pragma unroll
    for (int nf = 0; nf < 4; ++nf)
#pragma unroll
        for (int kk = 0; kk < 4; ++kk) {
            bf16x8 bfrag = *reinterpret_cast<const bf16x8*>(
                &Bs[(64 + nf * 16 + lr) * KP + kk * 32 + kg * 8]);
            acc_v[nf] = __builtin_amdgcn_mfma_f32_16x16x32_bf16(
                afrag[kk], bfrag, acc_v[nf], 0, 0, 0);
        }

    // ---- pW1 GEMM -> prob (in-register dot with pW2, DPP 16-lane reduce) ----
    {
        f32x4 acc[4];
#pragma unroll
        for (int nf = 0; nf < 4; ++nf) acc[nf] = (f32x4){0.f, 0.f, 0.f, 0.f};
#pragma unroll
        for (int nf = 0; nf < 4; ++nf)
#pragma unroll
            for (int kk = 0; kk < 4; ++kk) {
                bf16x8 bfrag = *reinterpret_cast<const bf16x8*>(
                    &Bs[(nf * 16 + lr) * KP + kk * 32 + kg * 8]);
                acc[nf] = __builtin_amdgcn_mfma_f32_16x16x32_bf16(
                    afrag[kk], bfrag, acc[nf], 0, 0, 0);
            }
        float pr[4] = {0.f, 0.f, 0.f, 0.f};
#pragma unroll
        for (int nf = 0; nf < 4; ++nf) {
            int col = nf * 16 + lr;
            float bi = pb1[col];
            float w2 = pW2[col];
#pragma unroll
            for (int j = 0; j < 4; ++j)
                pr[j] = fmaf(gelu_tanh(acc[nf][j] + bi), w2, pr[j]);
        }
#pragma unroll
        for (int j = 0; j < 4; ++j) {
            float v = dpp_add16(pr[j]);
            int row = row0 + wave * 16 + kg * 4 + j;
            if (lr == 0 && row < nrows) prob[row] = v + pb2[0];
        }
    }

    // ---- t2 = gelu(acc_v + vb1) -> LDS (As reused), stage vW2t -> Bs ----
    __syncthreads();    // all As/Bs reads done
    short* t2lds = As;  // [64][72]
#pragma unroll
    for (int nf = 0; nf < 4; ++nf) {
        int col = nf * 16 + lr;
        float bi = vb1[col];
#pragma unroll
        for (int j = 0; j < 4; ++j) {
            int r = wave * 16 + kg * 4 + j;
            t2lds[r * KP2 + col] = f2bf(gelu_tanh(acc_v[nf][j] + bi));
        }
    }
#pragma unroll
    for (int it = 0; it < 4; ++it) {     // vW2t: [128 n][64 k]
        int idx = tid + it * 256;
        int nn = idx >> 3, j = idx & 7;
        *reinterpret_cast<uint4*>(&Bs[nn * KP2 + j * 8]) =
            *reinterpret_cast<const uint4*>(&vW2t[nn * 64 + j * 8]);
    }
    __syncthreads();

    // ---- vol = t2 @ vW2 + vb2 (K=64, BN=128) ----
    bf16x8 a2[2];
#pragma unroll
    for (int kk = 0; kk < 2; ++kk)
        a2[kk] = *reinterpret_cast<const bf16x8*>(
            &t2lds[(wave * 16 + lr) * KP2 + kk * 32 + kg * 8]);
    f32x4 accv[8];
#pragma unroll
    for (int nf = 0; nf < 8; ++nf) accv[nf] = (f32x4){0.f, 0.f, 0.f, 0.f};
#pragma unroll
    for (int nf = 0; nf < 8; ++nf)
#pragma unroll
        for (int kk = 0; kk < 2; ++kk) {
            bf16x8 bfrag = *reinterpret_cast<const bf16x8*>(
                &Bs[(nf * 16 + lr) * KP2 + kk * 32 + kg * 8]);
            accv[nf] = __builtin_amdgcn_mfma_f32_16x16x32_bf16(
                a2[kk], bfrag, accv[nf], 0, 0, 0);
        }
#pragma unroll
    for (int nf = 0; nf < 8; ++nf) {
        int col = nf * 16 + lr;
        float bi = vb2[col];
#pragma unroll
        for (int j = 0; j < 4; ++j) {
            int row = row0 + wave * 16 + kg * 4 + j;
            if (row < nrows)
                vol[(size_t)row * 128 + col] = accv[nf][j] + bi;
        }
    }
}

extern "C" void kernel_launch(void* const* d_in, const int* in_sizes, int n_in,
                              void* d_out, int out_size, void* d_ws, size_t ws_size,
                              hipStream_t stream)
{
    const float* x      = (const float*)d_in[0];
    const int*   ei     = (const int*)  d_in[1];
    const float* Win    = (const float*)d_in[2];
    const float* b_in   = (const float*)d_in[3];
    const float* ln_g   = (const float*)d_in[4];
    const float* ln_b   = (const float*)d_in[5];
    const float* Wl     = (const float*)d_in[6];
    const float* bl     = (const float*)d_in[7];
    const float* Wr     = (const float*)d_in[8];
    const float* br     = (const float*)d_in[9];
    const float* att    = (const float*)d_in[10];
    const float* conv_b = (const float*)d_in[11];
    const float* fn_g   = (const float*)d_in[12];
    const float* fn_b   = (const float*)d_in[13];
    const float* pW1    = (const float*)d_in[14];
    const float* pb1    = (const float*)d_in[15];
    const float* pW2    = (const float*)d_in[16];
    const float* pb2    = (const float*)d_in[17];
    const float* vW1    = (const float*)d_in[18];
    const float* vb1    = (const float*)d_in[19];
    const float* vW2    = (const float*)d_in[20];
    const float* vb2    = (const float*)d_in[21];

    // workspace layout. padded counts (3.2MB) ALIASES ssrc: counts is dead
    // after compact; ssrc is first written in hybrid3.
    char* wp = (char*)d_ws;
    float* h    = (float*)wp; wp += (size_t)NN * 128 * 4;
    short* XL   = (short*)wp; wp += (size_t)NN * 128 * 2;
    short* XR   = (short*)wp; wp += (size_t)NN * 128 * 2;
    int* csr_scratch = (int*)wp; wp += (size_t)NPAD * CST * 4;  // counts / ssrc
    int* cc     = (int*)wp;   wp += (size_t)NPAD * 4;
    int* roff   = (int*)wp;   wp += (size_t)(NPAD + 16) * 4;
    int* pos    = (int*)wp;   wp += (size_t)EE * 4;
    short* Win_t = (short*)wp;
    short* Wl_t  = Win_t + 16384;
    short* Wr_t  = Wl_t + 3 * 16384;
    short* pW1_t = Wr_t + 3 * 16384;
    short* vW1_t = pW1_t + 8192;
    short* vW2_t = vW1_t + 8192;
    int* counts = csr_scratch;
    int* ssrc   = csr_scratch;
    float* vol  = (float*)d_out;
    float* prob = (float*)d_out + (size_t)NN * 128;

    WtArgs wa;
    wa.src[0] = Win;  wa.dst[0] = Win_t; wa.K[0] = 128; wa.N[0] = 128;
    for (int i = 0; i < 3; ++i) {
        wa.src[1 + i] = Wl + (size_t)i * 16384; wa.dst[1 + i] = Wl_t + i * 16384;
        wa.K[1 + i] = 128; wa.N[1 + i] = 128;
        wa.src[4 + i] = Wr + (size_t)i * 16384; wa.dst[4 + i] = Wr_t + i * 16384;
        wa.K[4 + i] = 128; wa.N[4 + i] = 128;
    }
    wa.src[7] = pW1; wa.dst[7] = pW1_t; wa.K[7] = 128; wa.N[7] = 64;
    wa.src[8] = vW1; wa.dst[8] = vW1_t; wa.K[8] = 128; wa.N[8] = 64;
    wa.src[9] = vW2; wa.dst[9] = vW2_t; wa.K[9] = 64;  wa.N[9] = 128;

    const int gemm_grid = (NN + 63) / 64;          // 782
    const int row_grid  = (NN + 3) / 4;

    // 1. zero padded counts
    hipMemsetAsync(counts, 0, (size_t)NPAD * CST * sizeof(int), stream);
    // 2. pos atomics (padded counts, unrolled x5) || weight prep
    hybrid1<<<EBLK + 160, 256, 0, stream>>>(ei, counts, pos, wa);
    // 3. compact padded counts -> contiguous cc (massively parallel)
    compact_kernel<<<NPAD / 256, 256, 0, stream>>>(counts, cc);
    // 4. scan (contiguous) || input projection
    hybrid2<<<1 + gemm_grid, 256, 0, stream>>>(cc, roff, x, Win_t, b_in, h, NN);
    // 5. scatter (unrolled x5) || layer-0 LN+GEMMs (ssrc overwrites counts region)
    hybrid3<<<EBLK + gemm_grid, 256, 0, stream>>>(ei, roff, pos, ssrc,
        h, ln_g, ln_b, Wl_t, bl, XL, Wr_t, br, XR, NN);
    // 6. gat layer 0
    gat_node_kernel<<<row_grid, 256, 0, stream>>>(
        XL, XR, roff, ssrc, att, conv_b, h);
    // 7-10. layers 1,2
    for (int i = 1; i < 3; ++i) {
        fused_layer<<<gemm_grid, 256, 0, stream>>>(
            h, ln_g + i * 128, ln_b + i * 128,
            Wl_t + i * 16384, bl + i * 128, XL,
            Wr_t + i * 16384, br + i * 128, XR, NN);
        gat_node_kernel<<<row_grid, 256, 0, stream>>>(
            XL, XR, roff, ssrc, att + i * 128, conv_b + i * 128, h);
    }
    // 11. final LN + both heads + vol GEMM, all in one kernel
    final_head_full<<<gemm_grid, 256, 0, stream>>>(
        h, fn_g, fn_b, pW1_t, pb1, pW2, pb2, vW1_t, vb1, vW2_t, vb2, vol, prob, NN);
}

// Round 18
// 352.627 us; speedup vs baseline: 1.0110x; 1.0110x over previous
//
#include <hip/hip_runtime.h>
#include <math.h>

constexpr int NN  = 50000;   // nodes
constexpr int EE  = 800000;  // edges
constexpr int NPAD = 50176;  // NN padded to 1024 multiple
constexpr float LOG2E = 1.4426950408889634f;
constexpr int CST = 16;      // counts stride (ints): 1 counter per 64B line

typedef short bf16x8 __attribute__((ext_vector_type(8)));
typedef float f32x4  __attribute__((ext_vector_type(4)));

__device__ __forceinline__ unsigned f2bfu(float f) {
    union { float f; unsigned u; } x; x.f = f;
    unsigned r = x.u + 0x7fffu + ((x.u >> 16) & 1u);
    return r >> 16;
}
__device__ __forceinline__ short f2bf(float f) { return (short)f2bfu(f); }
__device__ __forceinline__ unsigned pack2(float lo, float hi) {
    return f2bfu(lo) | (f2bfu(hi) << 16);
}
__device__ __forceinline__ float bfbits_lo(unsigned w) { return __uint_as_float(w << 16); }
__device__ __forceinline__ float bfbits_hi(unsigned w) { return __uint_as_float(w & 0xffff0000u); }

__device__ __forceinline__ float gelu_tanh(float x) {
    float u = 0.7978845608028654f * (x + 0.044715f * x * x * x);
    float t = 1.0f - 2.0f / (__expf(2.0f * u) + 1.0f);   // tanh(u)
    return 0.5f * x * (1.0f + t);
}

// 16-lane (DPP-row) sum reduce, broadcast to all 16 lanes.
__device__ __forceinline__ float dpp_add16(float x) {
    int t;
    t = __builtin_amdgcn_update_dpp(0, __float_as_int(x), 0xB1,  0xf, 0xf, true);
    x += __int_as_float(t);
    t = __builtin_amdgcn_update_dpp(0, __float_as_int(x), 0x4E,  0xf, 0xf, true);
    x += __int_as_float(t);
    t = __builtin_amdgcn_update_dpp(0, __float_as_int(x), 0x141, 0xf, 0xf, true);
    x += __int_as_float(t);
    t = __builtin_amdgcn_update_dpp(0, __float_as_int(x), 0x140, 0xf, 0xf, true);
    x += __int_as_float(t);
    return x;
}

// 8-lane sum reduce (xor1, xor2, half-row mirror), broadcast to the 8 lanes.
__device__ __forceinline__ float dpp_add8(float x) {
    int t;
    t = __builtin_amdgcn_update_dpp(0, __float_as_int(x), 0xB1,  0xf, 0xf, true);
    x += __int_as_float(t);
    t = __builtin_amdgcn_update_dpp(0, __float_as_int(x), 0x4E,  0xf, 0xf, true);
    x += __int_as_float(t);
    t = __builtin_amdgcn_update_dpp(0, __float_as_int(x), 0x141, 0xf, 0xf, true);
    x += __int_as_float(t);
    return x;
}

// -------- weight prep args --------
struct WtArgs {
    const float* src[10];
    short*       dst[10];
    int K[10];
    int N[10];
};

// -------- [LN] + 1-2 bf16 MFMA GEMMs (BN=128, K=128), LOW-LDS variant --------
// B staged in four 32-row quarters (Bs = 32x136 bf16) -> 26 KB LDS, 6 blocks/CU.
template<int NB, int DO_LN, int ACT, int OUTBF0, int OUTBF1>
__device__ __forceinline__ void ln_gemm_body(
    int row0, const float* __restrict__ A,
    const float* __restrict__ lg, const float* __restrict__ lb,
    const short* __restrict__ B0t, const float* __restrict__ bias0, void* __restrict__ C0,
    const short* __restrict__ B1t, const float* __restrict__ bias1, void* __restrict__ C1,
    int nrows, short* As /*[64*136]*/, short* Bs /*[32*136]*/)
{
    constexpr int K = 128, KP = 136, BN = 128;
    constexpr int CH = K / 8;           // 16 chunks/row
    const int tid = threadIdx.x;

    // ---- phase 1: load A (4 threads/row), optional LN, pack bf16 -> As ----
    {
        int r = tid >> 2, q = tid & 3;
        int grow = row0 + r;
        bool ok = grow < nrows;
        float4 v[8];
        const float* src = A + (size_t)grow * K + q * 32;
#pragma unroll
        for (int i = 0; i < 8; ++i)
            v[i] = ok ? *reinterpret_cast<const float4*>(src + i * 4)
                      : make_float4(0.f, 0.f, 0.f, 0.f);
        if (DO_LN) {
            float s = 0.f, s2 = 0.f;
#pragma unroll
            for (int i = 0; i < 8; ++i) {
                s  += v[i].x + v[i].y + v[i].z + v[i].w;
                s2 += v[i].x * v[i].x + v[i].y * v[i].y + v[i].z * v[i].z + v[i].w * v[i].w;
            }
            s += __shfl_xor(s, 1); s2 += __shfl_xor(s2, 1);
            s += __shfl_xor(s, 2); s2 += __shfl_xor(s2, 2);
            float mean = s * (1.f / 128.f);
            float var  = s2 * (1.f / 128.f) - mean * mean;
            float rstd = rsqrtf(var + 1e-5f);
#pragma unroll
            for (int i = 0; i < 8; ++i) {
                float4 gg = *reinterpret_cast<const float4*>(lg + q * 32 + i * 4);
                float4 bb = *reinterpret_cast<const float4*>(lb + q * 32 + i * 4);
                v[i].x = (v[i].x - mean) * rstd * gg.x + bb.x;
                v[i].y = (v[i].y - mean) * rstd * gg.y + bb.y;
                v[i].z = (v[i].z - mean) * rstd * gg.z + bb.z;
                v[i].w = (v[i].w - mean) * rstd * gg.w + bb.w;
            }
        }
        short* dst = &As[r * KP + q * 32];
#pragma unroll
        for (int i = 0; i < 4; ++i) {
            uint4 w = make_uint4(pack2(v[2*i].x,   v[2*i].y),
                                 pack2(v[2*i].z,   v[2*i].w),
                                 pack2(v[2*i+1].x, v[2*i+1].y),
                                 pack2(v[2*i+1].z, v[2*i+1].w));
            *reinterpret_cast<uint4*>(dst + i * 8) = w;
        }
    }
    __syncthreads();                    // As visible to all waves

    const int wave = tid >> 6;
    const int lane = tid & 63;
    const int kg   = lane >> 4;
    const int lr   = lane & 15;

    bf16x8 afrag[4];
#pragma unroll
    for (int kk = 0; kk < 4; ++kk)
        afrag[kk] = *reinterpret_cast<const bf16x8*>(
            &As[(wave * 16 + lr) * KP + kk * 32 + kg * 8]);

    // stage 32 rows (quarter q) of a [128][128] bf16 weight into Bs
    auto stageBq = [&](const short* __restrict__ Bt, int q) {
#pragma unroll
        for (int it = 0; it < 2; ++it) {
            int idx = tid + it * 256;          // 0..511
            int nn = idx / CH, j = idx % CH;   // nn 0..31
            *reinterpret_cast<uint4*>(&Bs[nn * KP + j * 8]) =
                *reinterpret_cast<const uint4*>(&Bt[(q * 32 + nn) * K + j * 8]);
        }
    };

    auto do_gemm = [&](const short* __restrict__ Bt,
                       const float* __restrict__ bias, void* __restrict__ Cv, bool outbf) {
        f32x4 acc[8];
#pragma unroll
        for (int nf = 0; nf < 8; ++nf) acc[nf] = (f32x4){0.f, 0.f, 0.f, 0.f};
#pragma unroll
        for (int q = 0; q < 4; ++q) {
            __syncthreads();            // previous quarter's reads done
            stageBq(Bt, q);
            __syncthreads();
#pragma unroll
            for (int l = 0; l < 2; ++l) {
                int nf = q * 2 + l;
#pragma unroll
                for (int kk = 0; kk < 4; ++kk) {
                    bf16x8 bfrag = *reinterpret_cast<const bf16x8*>(
                        &Bs[(l * 16 + lr) * KP + kk * 32 + kg * 8]);
                    acc[nf] = __builtin_amdgcn_mfma_f32_16x16x32_bf16(
                        afrag[kk], bfrag, acc[nf], 0, 0, 0);
                }
            }
        }
#pragma unroll
        for (int nf = 0; nf < 8; ++nf) {
            int col = nf * 16 + lr;
            float bi = bias[col];
#pragma unroll
            for (int j = 0; j < 4; ++j) {
                int row = row0 + wave * 16 + kg * 4 + j;
                if (row < nrows) {
                    float v = acc[nf][j] + bi;
                    if (ACT == 1) v = gelu_tanh(v);
                    if (outbf) ((short*)Cv)[(size_t)row * BN + col] = f2bf(v);
                    else       ((float*)Cv)[(size_t)row * BN + col] = v;
                }
            }
        }
    };

    do_gemm(B0t, bias0, C0, OUTBF0 != 0);
    if (NB == 2)
        do_gemm(B1t, bias1, C1, OUTBF1 != 0);
}

// ---------------- hybrid1: pos atomics (padded counts) || weight prep ----------------
__global__ __launch_bounds__(256) void hybrid1(
    const int* __restrict__ ei, int* __restrict__ counts, int* __restrict__ pos, WtArgs a)
{
    if (blockIdx.x < 1024) {
        for (int e = blockIdx.x * 256 + threadIdx.x; e < EE; e += 1024 * 256)
            pos[e] = atomicAdd(&counts[(size_t)ei[EE + e] * CST], 1);
    } else {
        int bb = blockIdx.x - 1024;
        int m = bb >> 4, slice = bb & 15;
        const float* s = a.src[m];
        short* d = a.dst[m];
        int K = a.K[m], N = a.N[m], total = K * N;
        for (int i = slice * 256 + threadIdx.x; i < total; i += 16 * 256) {
            int k = i / N, n = i - k * N;
            d[n * K + k] = f2bf(s[i]);
        }
    }
}

// ---------------- compact: cc[i] = counts[i*CST], massively parallel ----------------
__global__ __launch_bounds__(256) void compact_kernel(
    const int* __restrict__ counts, int* __restrict__ cc)
{
    int i = blockIdx.x * 256 + threadIdx.x;
    if (i < NPAD) cc[i] = counts[(size_t)i * CST];
}

// ---------------- scan (1 block, 256 threads, 4 elems/thread, contiguous cc) ----------------
__device__ void scan256(const int* __restrict__ cc, int* __restrict__ roff) {
    __shared__ int wsum[4];
    __shared__ int tilesum;
    int tid = threadIdx.x, wid = tid >> 6, lane = tid & 63;
    int carry = 0;
    for (int base = 0; base < NPAD; base += 1024) {
        int idx = base + tid * 4;
        int4 c = *reinterpret_cast<const int4*>(&cc[idx]);
        int s0 = c.x, s1 = s0 + c.y, s2 = s1 + c.z, s3 = s2 + c.w;
        int x = s3;
#pragma unroll
        for (int off = 1; off < 64; off <<= 1) {
            int t = __shfl_up(x, off);
            if (lane >= off) x += t;
        }
        if (lane == 63) wsum[wid] = x;
        __syncthreads();
        if (tid == 0) {
            int a0 = wsum[0], a1 = wsum[1], a2 = wsum[2], a3 = wsum[3];
            wsum[0] = 0; wsum[1] = a0; wsum[2] = a0 + a1; wsum[3] = a0 + a1 + a2;
            tilesum = a0 + a1 + a2 + a3;
        }
        __syncthreads();
        int start = carry + wsum[wid] + (x - s3);      // exclusive prefix at idx
        int4 o = make_int4(start, start + s0, start + s1, start + s2);
        *reinterpret_cast<int4*>(&roff[idx]) = o;
        carry += tilesum;
        __syncthreads();
    }
}

// ---------------- hybrid2: scan (block 0) || input projection ----------------
__global__ __launch_bounds__(256) void hybrid2(
    const int* __restrict__ cc, int* __restrict__ roff,
    const float* __restrict__ x, const short* __restrict__ Win_t,
    const float* __restrict__ b_in, float* __restrict__ h, int nrows)
{
    __shared__ short As[64 * 136];
    __shared__ short Bs[32 * 136];
    if (blockIdx.x == 0) {
        scan256(cc, roff);
    } else {
        ln_gemm_body<1, 0, 0, 0, 0>((blockIdx.x - 1) * 64, x, nullptr,
            nullptr, Win_t, b_in, h, nullptr, nullptr, nullptr, nrows, As, Bs);
    }
}

// ---------------- hybrid3: scatter (blocks 0..511) || layer-0 LN+GEMMs ----------------
__global__ __launch_bounds__(256) void hybrid3(
    const int* __restrict__ ei, const int* __restrict__ roff,
    const int* __restrict__ pos, int* __restrict__ ssrc,
    const float* __restrict__ h, const float* __restrict__ lg, const float* __restrict__ lb,
    const short* __restrict__ Wl_t, const float* __restrict__ bl, short* __restrict__ XL,
    const short* __restrict__ Wr_t, const float* __restrict__ br, short* __restrict__ XR,
    int nrows)
{
    __shared__ short As[64 * 136];
    __shared__ short Bs[32 * 136];
    if (blockIdx.x < 512) {
        for (int e = blockIdx.x * 256 + threadIdx.x; e < EE; e += 512 * 256)
            ssrc[roff[ei[EE + e]] + pos[e]] = ei[e] << 8;   // pre-shifted byte offset
    } else {
        ln_gemm_body<2, 1, 0, 1, 1>((blockIdx.x - 512) * 64, h,
            lg, lb, Wl_t, bl, XL, Wr_t, br, XR, nrows, As, Bs);
    }
}

// ---------------- standalone fused LN + Wl/Wr GEMMs (layers 1,2) ----------------
__global__ __launch_bounds__(256) void fused_layer(
    const float* __restrict__ h, const float* __restrict__ lg, const float* __restrict__ lb,
    const short* __restrict__ Wl_t, const float* __restrict__ bl, short* __restrict__ XL,
    const short* __restrict__ Wr_t, const float* __restrict__ br, short* __restrict__ XR,
    int nrows)
{
    __shared__ short As[64 * 136];
    __shared__ short Bs[32 * 136];
    ln_gemm_body<2, 1, 0, 1, 1>(blockIdx.x * 64, h, lg, lb,
        Wl_t, bl, XL, Wr_t, br, XR, nrows, As, Bs);
}

// ---------------- Fused GATv2 aggregation, one wave per node (R13/R14 version) ----------------
__global__ __launch_bounds__(256) void gat_node_kernel(
    const short* __restrict__ XL, const short* __restrict__ XR,
    const int* __restrict__ roff, const int* __restrict__ ssrc,
    const float* __restrict__ att, const float* __restrict__ conv_b,
    float* __restrict__ h)
{
    int n = blockIdx.x * 4 + (threadIdx.x >> 6);
    if (n >= NN) return;
    const int lane = threadIdx.x & 63;
    const int half = lane >> 5;          // edge slot within a pass
    const int pos  = lane & 31;          // channels pos*4 .. pos*4+3

    uint2 wr2 = *reinterpret_cast<const uint2*>(&XR[(size_t)n * 128 + pos * 4]);
    const float xr0 = bfbits_lo(wr2.x), xr1 = bfbits_hi(wr2.x);
    const float xr2 = bfbits_lo(wr2.y), xr3 = bfbits_hi(wr2.y);
    float4 at = *reinterpret_cast<const float4*>(&att[pos * 4]);
    const float a6_0 = at.x * (0.6f * LOG2E), a4_0 = at.x * (0.4f * LOG2E);
    const float a6_1 = at.y * (0.6f * LOG2E), a4_1 = at.y * (0.4f * LOG2E);
    const float a6_2 = at.z * (0.6f * LOG2E), a4_2 = at.z * (0.4f * LOG2E);
    const float a6_3 = at.w * (0.6f * LOG2E), a4_3 = at.w * (0.4f * LOG2E);

    float dA = 0.f, dB = 0.f;
    float aA0 = 0.f, aA1 = 0.f, aA2 = 0.f, aA3 = 0.f;
    float aB0 = 0.f, aB1 = 0.f, aB2 = 0.f, aB3 = 0.f;

    const char* XLb = (const char*)XL;
    const unsigned lbyte = (unsigned)pos * 8u;

    auto proc = [&](uint2 w, bool valid, float& d,
                    float& a0, float& a1, float& a2, float& a3) {
        float x0 = bfbits_lo(w.x), x1 = bfbits_hi(w.x);
        float x2 = bfbits_lo(w.y), x3 = bfbits_hi(w.y);
        float s0 = x0 + xr0, s1 = x1 + xr1, s2 = x2 + xr2, s3 = x3 + xr3;
        float part =
            fmaf(s0, a6_0, fmaf(__builtin_fabsf(s0), a4_0,
            fmaf(s1, a6_1, fmaf(__builtin_fabsf(s1), a4_1,
            fmaf(s2, a6_2, fmaf(__builtin_fabsf(s2), a4_2,
            fmaf(s3, a6_3, __builtin_fabsf(s3) * a4_3)))))));
        part = dpp_add8(part);               // head dot: 8 lanes x 4 ch
        float pe = __builtin_amdgcn_exp2f(part);
        if (!valid) pe = 0.f;
        d += pe;
        a0 = fmaf(pe, x0, a0);
        a1 = fmaf(pe, x1, a1);
        a2 = fmaf(pe, x2, a2);
        a3 = fmaf(pe, x3, a3);
    };

    const int beg = roff[n], end = roff[n + 1];
    int p = beg;
    for (; p + 3 < end; p += 4) {
        unsigned oA = (unsigned)ssrc[p + half]     + lbyte;
        unsigned oB = (unsigned)ssrc[p + 2 + half] + lbyte;
        uint2 wA = *reinterpret_cast<const uint2*>(XLb + oA);
        uint2 wB = *reinterpret_cast<const uint2*>(XLb + oB);
        proc(wA, true, dA, aA0, aA1, aA2, aA3);
        proc(wB, true, dB, aB0, aB1, aB2, aB3);
    }
    if (p < end) {
        int eA = p + half;
        bool vA = eA < end;
        unsigned oA = (unsigned)ssrc[vA ? eA : beg] + lbyte;
        uint2 wA = *reinterpret_cast<const uint2*>(XLb + oA);
        proc(wA, vA, dA, aA0, aA1, aA2, aA3);
        if (p + 2 < end) {
            int eB = p + 2 + half;
            bool vB = eB < end;
            unsigned oB = (unsigned)ssrc[vB ? eB : beg] + lbyte;
            uint2 wB = *reinterpret_cast<const uint2*>(XLb + oB);
            proc(wB, vB, dB, aB0, aB1, aB2, aB3);
        }
    }
    float d  = dA + dB;
    float c0 = aA0 + aB0, c1 = aA1 + aB1, c2 = aA2 + aB2, c3 = aA3 + aB3;
    d  += __shfl_xor(d, 32);
    c0 += __shfl_xor(c0, 32);
    c1 += __shfl_xor(c1, 32);
    c2 += __shfl_xor(c2, 32);
    c3 += __shfl_xor(c3, 32);

    if (half == 0) {
        float inv = 1.f / (d + 1e-16f);
        float* hp = &h[(size_t)n * 128 + pos * 4];
        float4 hv = *reinterpret_cast<const float4*>(hp);
        float4 cb = *reinterpret_cast<const float4*>(&conv_b[pos * 4]);
        hv.x += gelu_tanh(fmaf(c0, inv, cb.x));
        hv.y += gelu_tanh(fmaf(c1, inv, cb.y));
        hv.z += gelu_tanh(fmaf(c2, inv, cb.z));
        hv.w += gelu_tanh(fmaf(c3, inv, cb.w));
        *reinterpret_cast<float4*>(hp) = hv;
    }
}

// -------- final: LN -> {prob head fused, vol = gelu(z@vW1+vb1) @ vW2 + vb2} --------
__global__ __launch_bounds__(256) void final_head_full(
    const float* __restrict__ A,
    const float* __restrict__ lg, const float* __restrict__ lb,
    const short* __restrict__ pW1t, const float* __restrict__ pb1,
    const float* __restrict__ pW2, const float* __restrict__ pb2,
    const short* __restrict__ vW1t, const float* __restrict__ vb1,
    const short* __restrict__ vW2t, const float* __restrict__ vb2,
    float* __restrict__ vol, float* __restrict__ prob, int nrows)
{
    constexpr int K = 128, KP = 136, KP2 = 72;
    constexpr int CH = K / 8;
    __shared__ short As[64 * 136];   // LN'd input; later reused as t2 tile [64][72]
    __shared__ short Bs[128 * 136];  // pW1t rows 0-63, vW1t rows 64-127; later vW2t

    const int tid  = threadIdx.x;
    const int row0 = blockIdx.x * 64;

    // LN -> As
    {
        int r = tid >> 2, q = tid & 3;
        int grow = row0 + r;
        bool ok = grow < nrows;
        float4 v[8];
        const float* src = A + (size_t)grow * K + q * 32;
#pragma unroll
        for (int i = 0; i < 8; ++i)
            v[i] = ok ? *reinterpret_cast<const float4*>(src + i * 4)
                      : make_float4(0.f, 0.f, 0.f, 0.f);
        float s = 0.f, s2 = 0.f;
#pragma unroll
        for (int i = 0; i < 8; ++i) {
            s  += v[i].x + v[i].y + v[i].z + v[i].w;
            s2 += v[i].x * v[i].x + v[i].y * v[i].y + v[i].z * v[i].z + v[i].w * v[i].w;
        }
        s += __shfl_xor(s, 1); s2 += __shfl_xor(s2, 1);
        s += __shfl_xor(s, 2); s2 += __shfl_xor(s2, 2);
        float mean = s * (1.f / 128.f);
        float var  = s2 * (1.f / 128.f) - mean * mean;
        float rstd = rsqrtf(var + 1e-5f);
        short* dst = &As[r * KP + q * 32];
#pragma unroll
        for (int i = 0; i < 8; ++i) {
            float4 gg = *reinterpret_cast<const float4*>(lg + q * 32 + i * 4);
            float4 bb = *reinterpret_cast<const float4*>(lb + q * 32 + i * 4);
            v[i].x = (v[i].x - mean) * rstd * gg.x + bb.x;
            v[i].y = (v[i].y - mean) * rstd * gg.y + bb.y;
            v[i].z = (v[i].z - mean) * rstd * gg.z + bb.z;
            v[i].w = (v[i].w - mean) * rstd * gg.w + bb.w;
        }
#pragma unroll
        for (int i = 0; i < 4; ++i) {
            uint4 w = make_uint4(pack2(v[2*i].x,   v[2*i].y),
                                 pack2(v[2*i].z,   v[2*i].w),
                                 pack2(v[2*i+1].x, v[2*i+1].y),
                                 pack2(v[2*i+1].z, v[2*i+1].w));
            *reinterpret_cast<uint4*>(dst + i * 8) = w;
        }
    }
    // stage pW1t | vW1t
#pragma unroll
    for (int it = 0; it < 8; ++it) {
        int idx = tid + it * 256;
        int nn = idx / CH, j = idx % CH;
        const short* srcw = (nn < 64) ? &pW1t[nn * K + j * 8]
                                      : &vW1t[(nn - 64) * K + j * 8];
        *reinterpret_cast<uint4*>(&Bs[nn * KP + j * 8]) =
            *reinterpret_cast<const uint4*>(srcw);
    }
    __syncthreads();

    const int wave = tid >> 6;
    const int lane = tid & 63;
    const int kg   = lane >> 4;
    const int lr   = lane & 15;

    bf16x8 afrag[4];
#pragma unroll
    for (int kk = 0; kk < 4; ++kk)
        afrag[kk] = *reinterpret_cast<const bf16x8*>(
            &As[(wave * 16 + lr) * KP + kk * 32 + kg * 8]);

    // ---- vW1 GEMM -> acc_v (keep in regs) ----
    f32x4 acc_v[4];
#pragma unroll
    for (int nf = 0; nf < 4; ++nf) acc_v[nf] = (f32x4){0.f, 0.f, 0.f, 0.f};
#pragma unroll
    for (int nf = 0; nf < 4; ++nf)
#pragma unroll
        for (int kk = 0; kk < 4; ++kk) {
            bf16x8 bfrag = *reinterpret_cast<const bf16x8*>(
                &Bs[(64 + nf * 16 + lr) * KP + kk * 32 + kg * 8]);
            acc_v[nf] = __builtin_amdgcn_mfma_f32_16x16x32_bf16(
                afrag[kk], bfrag, acc_v[nf], 0, 0, 0);
        }

    // ---- pW1 GEMM -> prob (in-register dot with pW2, DPP 16-lane reduce) ----
    {
        f32x4 acc[4];
#pragma unroll
        for (int nf = 0; nf < 4; ++nf) acc[nf] = (f32x4){0.f, 0.f, 0.f, 0.f};
#pragma unroll
        for (int nf = 0; nf < 4; ++nf)
#pragma unroll
            for (int kk = 0; kk < 4; ++kk) {
                bf16x8 bfrag = *reinterpret_cast<const bf16x8*>(
                    &Bs[(nf * 16 + lr) * KP + kk * 32 + kg * 8]);
                acc[nf] = __builtin_amdgcn_mfma_f32_16x16x32_bf16(
                    afrag[kk], bfrag, acc[nf], 0, 0, 0);
            }
        float pr[4] = {0.f, 0.f, 0.f, 0.f};
#pragma unroll
        for (int nf = 0; nf < 4; ++nf) {
            int col = nf * 16 + lr;
            float bi = pb1[col];
            float w2 = pW2[col];
#pragma unroll
            for (int j = 0; j < 4; ++j)
                pr[j] = fmaf(gelu_tanh(acc[nf][j] + bi), w2, pr[j]);
        }
#pragma unroll
        for (int j = 0; j < 4; ++j) {
            float v = dpp_add16(pr[j]);
            int row = row0 + wave * 16 + kg * 4 + j;
            if (lr == 0 && row < nrows) prob[row] = v + pb2[0];
        }
    }

    // ---- t2 = gelu(acc_v + vb1) -> LDS (As reused), stage vW2t -> Bs ----
    __syncthreads();    // all As/Bs reads done
    short* t2lds = As;  // [64][72]
#pragma unroll
    for (int nf = 0; nf < 4; ++nf) {
        int col = nf * 16 + lr;
        float bi = vb1[col];
#pragma unroll
        for (int j = 0; j < 4; ++j) {
            int r = wave * 16 + kg * 4 + j;
            t2lds[r * KP2 + col] = f2bf(gelu_tanh(acc_v[nf][j] + bi));
        }
    }
#pragma unroll
    for (int it = 0; it < 4; ++it) {     // vW2t: [128 n][64 k]
        int idx = tid + it * 256;
        int nn = idx >> 3, j = idx & 7;
        *reinterpret_cast<uint4*>(&Bs[nn * KP2 + j * 8]) =
            *reinterpret_cast<const uint4*>(&vW2t[nn * 64 + j * 8]);
    }
    __syncthreads();

    // ---- vol = t2 @ vW2 + vb2 (K=64, BN=128) ----
    bf16x8 a2[2];
#pragma unroll
    for (int kk = 0; kk < 2; ++kk)
        a2[kk] = *reinterpret_cast<const bf16x8*>(
            &t2lds[(wave * 16 + lr) * KP2 + kk * 32 + kg * 8]);
    f32x4 accv[8];
#pragma unroll
    for (int nf = 0; nf < 8; ++nf) accv[nf] = (f32x4){0.f, 0.f, 0.f, 0.f};
#pragma unroll
    for (int nf = 0; nf < 8; ++nf)
#pragma unroll
        for (int kk = 0; kk < 2; ++kk) {
            bf16x8 bfrag = *reinterpret_cast<const bf16x8*>(
                &Bs[(nf * 16 + lr) * KP2 + kk * 32 + kg * 8]);
            accv[nf] = __builtin_amdgcn_mfma_f32_16x16x32_bf16(
                a2[kk], bfrag, accv[nf], 0, 0, 0);
        }
#pragma unroll
    for (int nf = 0; nf < 8; ++nf) {
        int col = nf * 16 + lr;
        float bi = vb2[col];
#pragma unroll
        for (int j = 0; j < 4; ++j) {
            int row = row0 + wave * 16 + kg * 4 + j;
            if (row < nrows)
                vol[(size_t)row * 128 + col] = accv[nf][j] + bi;
        }
    }
}

extern "C" void kernel_launch(void* const* d_in, const int* in_sizes, int n_in,
                              void* d_out, int out_size, void* d_ws, size_t ws_size,
                              hipStream_t stream)
{
    const float* x      = (const float*)d_in[0];
    const int*   ei     = (const int*)  d_in[1];
    const float* Win    = (const float*)d_in[2];
    const float* b_in   = (const float*)d_in[3];
    const float* ln_g   = (const float*)d_in[4];
    const float* ln_b   = (const float*)d_in[5];
    const float* Wl     = (const float*)d_in[6];
    const float* bl     = (const float*)d_in[7];
    const float* Wr     = (const float*)d_in[8];
    const float* br     = (const float*)d_in[9];
    const float* att    = (const float*)d_in[10];
    const float* conv_b = (const float*)d_in[11];
    const float* fn_g   = (const float*)d_in[12];
    const float* fn_b   = (const float*)d_in[13];
    const float* pW1    = (const float*)d_in[14];
    const float* pb1    = (const float*)d_in[15];
    const float* pW2    = (const float*)d_in[16];
    const float* pb2    = (const float*)d_in[17];
    const float* vW1    = (const float*)d_in[18];
    const float* vb1    = (const float*)d_in[19];
    const float* vW2    = (const float*)d_in[20];
    const float* vb2    = (const float*)d_in[21];

    // workspace layout. padded counts (3.2MB) ALIASES ssrc: counts is dead
    // after compact; ssrc is first written in hybrid3.
    char* wp = (char*)d_ws;
    float* h    = (float*)wp; wp += (size_t)NN * 128 * 4;
    short* XL   = (short*)wp; wp += (size_t)NN * 128 * 2;
    short* XR   = (short*)wp; wp += (size_t)NN * 128 * 2;
    int* csr_scratch = (int*)wp; wp += (size_t)NPAD * CST * 4;  // counts / ssrc
    int* cc     = (int*)wp;   wp += (size_t)NPAD * 4;
    int* roff   = (int*)wp;   wp += (size_t)(NPAD + 16) * 4;
    int* pos    = (int*)wp;   wp += (size_t)EE * 4;
    short* Win_t = (short*)wp;
    short* Wl_t  = Win_t + 16384;
    short* Wr_t  = Wl_t + 3 * 16384;
    short* pW1_t = Wr_t + 3 * 16384;
    short* vW1_t = pW1_t + 8192;
    short* vW2_t = vW1_t + 8192;
    int* counts = csr_scratch;
    int* ssrc   = csr_scratch;
    float* vol  = (float*)d_out;
    float* prob = (float*)d_out + (size_t)NN * 128;

    WtArgs wa;
    wa.src[0] = Win;  wa.dst[0] = Win_t; wa.K[0] = 128; wa.N[0] = 128;
    for (int i = 0; i < 3; ++i) {
        wa.src[1 + i] = Wl + (size_t)i * 16384; wa.dst[1 + i] = Wl_t + i * 16384;
        wa.K[1 + i] = 128; wa.N[1 + i] = 128;
        wa.src[4 + i] = Wr + (size_t)i * 16384; wa.dst[4 + i] = Wr_t + i * 16384;
        wa.K[4 + i] = 128; wa.N[4 + i] = 128;
    }
    wa.src[7] = pW1; wa.dst[7] = pW1_t; wa.K[7] = 128; wa.N[7] = 64;
    wa.src[8] = vW1; wa.dst[8] = vW1_t; wa.K[8] = 128; wa.N[8] = 64;
    wa.src[9] = vW2; wa.dst[9] = vW2_t; wa.K[9] = 64;  wa.N[9] = 128;

    const int gemm_grid = (NN + 63) / 64;          // 782
    const int row_grid  = (NN + 3) / 4;

    // 1. zero padded counts
    hipMemsetAsync(counts, 0, (size_t)NPAD * CST * sizeof(int), stream);
    // 2. pos atomics (padded counts) || weight prep
    hybrid1<<<1024 + 160, 256, 0, stream>>>(ei, counts, pos, wa);
    // 3. compact padded counts -> contiguous cc (massively parallel)
    compact_kernel<<<NPAD / 256, 256, 0, stream>>>(counts, cc);
    // 4. scan (contiguous) || input projection
    hybrid2<<<1 + gemm_grid, 256, 0, stream>>>(cc, roff, x, Win_t, b_in, h, NN);
    // 5. scatter || layer-0 LN+GEMMs (ssrc overwrites the counts region)
    hybrid3<<<512 + gemm_grid, 256, 0, stream>>>(ei, roff, pos, ssrc,
        h, ln_g, ln_b, Wl_t, bl, XL, Wr_t, br, XR, NN);
    // 6. gat layer 0
    gat_node_kernel<<<row_grid, 256, 0, stream>>>(
        XL, XR, roff, ssrc, att, conv_b, h);
    // 7-10. layers 1,2
    for (int i = 1; i < 3; ++i) {
        fused_layer<<<gemm_grid, 256, 0, stream>>>(
            h, ln_g + i * 128, ln_b + i * 128,
            Wl_t + i * 16384, bl + i * 128, XL,
            Wr_t + i * 16384, br + i * 128, XR, NN);
        gat_node_kernel<<<row_grid, 256, 0, stream>>>(
            XL, XR, roff, ssrc, att + i * 128, conv_b + i * 128, h);
    }
    // 11. final LN + both heads + vol GEMM, all in one kernel
    final_head_full<<<gemm_grid, 256, 0, stream>>>(
        h, fn_g, fn_b, pW1_t, pb1, pW2, pb2, vW1_t, vb1, vW2_t, vb2, vol, prob, NN);
}